// Round 18
// baseline (495.070 us; speedup 1.0000x reference)
//
#include <hip/hip_runtime.h>
#include <math.h>

typedef unsigned short u16;
typedef __attribute__((ext_vector_type(8))) short bf8;    // 8 bf16 in 4 VGPRs
typedef __attribute__((ext_vector_type(8))) unsigned short u16x8;
typedef __attribute__((ext_vector_type(4))) float f32x4;

constexpr int NB = 32;      // batch
constexpr int NP = 196;     // pixels
constexpr int NE = 2048;    // encoder dim
constexpr int ED = 512;     // embedding dim
constexpr int HH = 512;     // hidden
constexpr int AA = 512;     // attention dim
constexpr int NV = 10000;   // vocab
constexpr int NT = 20;      // timesteps

__device__ inline u16 f2bf(float f) {
    unsigned u = __builtin_bit_cast(unsigned, f);
    u += 0x7fffu + ((u >> 16) & 1u);          // RNE
    return (u16)(u >> 16);
}
__device__ inline float bf2f(u16 h) {
    return __builtin_bit_cast(float, (unsigned)h << 16);
}
// 32 elems/thread: 8 independent nontemporal 16B loads issued before any
// convert/store -> 4x the per-thread MLP of the old 8-wide version (r18;
// convert was stuck at 2.5 TB/s = latency-bound, not BW-bound).
__device__ inline void cvt32(const float* __restrict__ s, u16* __restrict__ d) {
    f32x4 v[8];
#pragma unroll
    for (int i = 0; i < 8; ++i)
        v[i] = __builtin_nontemporal_load((const f32x4*)(s + i * 4));
#pragma unroll
    for (int i = 0; i < 4; ++i) {
        u16x8 o;
#pragma unroll
        for (int q = 0; q < 4; ++q) {
            o[q] = f2bf(v[2 * i][q]);
            o[4 + q] = f2bf(v[2 * i + 1][q]);
        }
        *(u16x8*)(d + i * 8) = o;
    }
}

// async global->LDS, 16 bytes per lane (global_load_lds_dwordx4)
__device__ inline void gld16(const u16* g, u16* l) {
    __builtin_amdgcn_global_load_lds(
        (const __attribute__((address_space(1))) void*)g,
        (__attribute__((address_space(3))) void*)l, 16, 0, 0);
}

// ---------------------------------------------------------------------------
// one-shot: convert X + all weights to bf16 (32 elems/thread), gather
// embeddings, zero c and h. Units of 32 elems; total 810240 = 256*3165.
// ---------------------------------------------------------------------------
__global__ void k_convert(const float* __restrict__ enc, const float* __restrict__ enc_W,
                          const float* __restrict__ dec_W, const float* __restrict__ W_ih,
                          const float* __restrict__ W_hh, const float* __restrict__ fc_W,
                          const float* __restrict__ emb, const int* __restrict__ caps,
                          u16* __restrict__ Xbf, u16* __restrict__ Wencbf,
                          u16* __restrict__ decWbf, u16* __restrict__ Wihbf,
                          u16* __restrict__ Whhbf, u16* __restrict__ fcWbf,
                          u16* __restrict__ embg, float* __restrict__ cbuf,
                          u16* __restrict__ hbf) {
    long u = (long)blockIdx.x * 256 + threadIdx.x;   // 32-element units
    if (u < 401408) { cvt32(enc + u * 32, Xbf + u * 32); return; }
    u -= 401408;
    if (u < 32768) { cvt32(enc_W + u * 32, Wencbf + u * 32); return; }
    u -= 32768;
    if (u < 8192) { cvt32(dec_W + u * 32, decWbf + u * 32); return; }
    u -= 8192;
    if (u < 163840) { cvt32(W_ih + u * 32, Wihbf + u * 32); return; }
    u -= 163840;
    if (u < 32768) { cvt32(W_hh + u * 32, Whhbf + u * 32); return; }
    u -= 32768;
    if (u < 160000) { cvt32(fc_W + u * 32, fcWbf + u * 32); return; }
    u -= 160000;
    if (u < 10240) {   // emb gather: embg[b][t][512]; row = 16 units
        long w = u >> 4, e = (u & 15) * 32;
        long b = w / 20, t = w - b * 20;
        int tok = caps[b * 21 + t];
        cvt32(emb + (size_t)tok * 512 + e, embg + (size_t)w * 512 + e);
        return;
    }
    u -= 10240;
    if (u < 512) {     // zero c: 32 f32 per thread
        float4 z = make_float4(0.f, 0.f, 0.f, 0.f);
#pragma unroll
        for (int i = 0; i < 8; ++i) *(float4*)(cbuf + u * 32 + i * 4) = z;
        return;
    }
    u -= 512;
    if (u < 512) {     // zero h: 32 u16 per thread
        u16x8 z = {};
#pragma unroll
        for (int i = 0; i < 4; ++i) *(u16x8*)(hbf + u * 32 + i * 8) = z;
    }
}

// ---------------------------------------------------------------------------
// MERGED front GEMM: [enc_proj | XW] = X(6272x2048) @ [enc_W ; Wctx]^T
// (N = 2560). m97 structure, 128x128 tile, grid (49,20) = 980 blocks.
// T1 XCD bijective swizzle (r10). Static LDS x2 unroll (r12).
// r16 lesson: counted-vmcnt graft on this 2-phase structure is NULL.
// ---------------------------------------------------------------------------
__global__ __launch_bounds__(256) void k_encxw(const u16* __restrict__ Xbf,
                                               const u16* __restrict__ Wencbf,
                                               const u16* __restrict__ Wihbf,
                                               const float* __restrict__ enc_b,
                                               u16* __restrict__ encprojbf,
                                               u16* __restrict__ XWbf) {
    __shared__ u16 As0[128 * 32], As1[128 * 32];
    __shared__ u16 Bs0[128 * 32], Bs1[128 * 32];
    int tid = threadIdx.x, lane = tid & 63, w = tid >> 6;
    int wr = w >> 1, wc = w & 1;

    // bijective XCD swizzle (nwg = 980 = 8*122 + 4)
    int old = blockIdx.y * 49 + blockIdx.x;
    int xcd = old & 7, off = old >> 3;
    int nid = (xcd < 4 ? xcd * 123 : 492 + (xcd - 4) * 122) + off;
    int i0 = (nid / 20) * 128, j0 = (nid % 20) * 128;

    int ar = lane & 15, kg = lane >> 4;

    int srow = tid >> 2;                 // 0..63
    int sc = (tid & 3) * 8;              // u16 col within 32
    const u16* gA0 = Xbf + (size_t)(i0 + srow) * NE + sc;
    const u16* gA1 = gA0 + (size_t)64 * NE;
    size_t bstr;
    const u16* gB0;
    if (j0 < 512) { bstr = 2048; gB0 = Wencbf + (size_t)(j0 + srow) * 2048 + sc; }
    else          { bstr = 2560; gB0 = Wihbf + (size_t)(j0 - 512 + srow) * 2560 + 512 + sc; }
    const u16* gB1 = gB0 + 64 * bstr;

    f32x4 acc[4][4] = {};

#define STAGE_EX(A_, B_, k0)                                \
    do {                                                    \
        gld16(gA0 + (k0), &A_[tid * 8]);                    \
        gld16(gA1 + (k0), &A_[2048 + tid * 8]);             \
        gld16(gB0 + (k0), &B_[tid * 8]);                    \
        gld16(gB1 + (k0), &B_[2048 + tid * 8]);             \
    } while (0)

#define COMPUTE_EX(A_, B_)                                                     \
    do {                                                                       \
        bf8 a[4], b[4];                                                        \
        _Pragma("unroll") for (int m = 0; m < 4; ++m)                          \
            a[m] = *(const bf8*)(&A_[(wr * 64 + m * 16 + ar) * 32 + kg * 8]);  \
        _Pragma("unroll") for (int n = 0; n < 4; ++n)                          \
            b[n] = *(const bf8*)(&B_[(wc * 64 + n * 16 + ar) * 32 + kg * 8]);  \
        _Pragma("unroll") for (int m = 0; m < 4; ++m)                          \
            _Pragma("unroll") for (int n = 0; n < 4; ++n)                      \
                acc[m][n] = __builtin_amdgcn_mfma_f32_16x16x32_bf16(           \
                    a[m], b[n], acc[m][n], 0, 0, 0);                           \
    } while (0)

    STAGE_EX(As0, Bs0, 0);
    __syncthreads();
    for (int ks = 0; ks < 64; ks += 2) {
        STAGE_EX(As1, Bs1, (ks + 1) * 32);
        COMPUTE_EX(As0, Bs0);
        __syncthreads();
        if (ks < 62) STAGE_EX(As0, Bs0, (ks + 2) * 32);
        COMPUTE_EX(As1, Bs1);
        if (ks < 62) __syncthreads();
    }
#undef STAGE_EX
#undef COMPUTE_EX

    int rbase = kg * 4;
    if (j0 < 512) {
#pragma unroll
        for (int m = 0; m < 4; ++m) {
            int row = i0 + wr * 64 + m * 16 + rbase;
#pragma unroll
            for (int n = 0; n < 4; ++n) {
                int col = j0 + wc * 64 + n * 16 + ar;
                float bias = enc_b[col];
#pragma unroll
                for (int r = 0; r < 4; ++r)
                    encprojbf[(size_t)(row + r) * AA + col] = f2bf(acc[m][n][r] + bias);
            }
        }
    } else {
#pragma unroll
        for (int m = 0; m < 4; ++m) {
            int row = i0 + wr * 64 + m * 16 + rbase;
#pragma unroll
            for (int n = 0; n < 4; ++n) {
                int col = j0 - 512 + wc * 64 + n * 16 + ar;
#pragma unroll
                for (int r = 0; r < 4; ++r)
                    XWbf[(size_t)(row + r) * 2048 + col] = f2bf(acc[m][n][r]);
            }
        }
    }
}

// ---------------------------------------------------------------------------
// gpre = embg(640x512) @ Wemb^T -> f32[640][2048], Wemb = W_ih[:, 0:512].
// ---------------------------------------------------------------------------
__global__ __launch_bounds__(256) void k_gpre(const u16* __restrict__ embg,
                                              const u16* __restrict__ Wihbf,
                                              float* __restrict__ gpre) {
    __shared__ u16 As[2][64 * 32];
    __shared__ u16 Bs[2][128 * 32];
    int tid = threadIdx.x, lane = tid & 63, w = tid >> 6;
    int wr = w >> 1, wc = w & 1;
    int i0 = blockIdx.x * 64, j0 = blockIdx.y * 128;
    int ar = lane & 15, kg = lane >> 4;

    int srow = tid >> 2;
    int sc = (tid & 3) * 8;
    const u16* gA  = embg + (size_t)(i0 + srow) * 512 + sc;
    const u16* gB0 = Wihbf + (size_t)(j0 + srow) * 2560 + sc;
    const u16* gB1 = Wihbf + (size_t)(j0 + 64 + srow) * 2560 + sc;

    f32x4 acc[2][4] = {};

#define STAGE_GP(buf, k0)                                   \
    do {                                                    \
        gld16(gA + (k0), &As[buf][tid * 8]);                \
        gld16(gB0 + (k0), &Bs[buf][tid * 8]);               \
        gld16(gB1 + (k0), &Bs[buf][2048 + tid * 8]);        \
    } while (0)

    STAGE_GP(0, 0);
    __syncthreads();
    for (int ks = 0; ks < 16; ++ks) {
        int cur = ks & 1;
        if (ks < 15) STAGE_GP(cur ^ 1, (ks + 1) * 32);
        bf8 a[2], b[4];
#pragma unroll
        for (int m = 0; m < 2; ++m)
            a[m] = *(const bf8*)(&As[cur][(wr * 32 + m * 16 + ar) * 32 + kg * 8]);
#pragma unroll
        for (int n = 0; n < 4; ++n)
            b[n] = *(const bf8*)(&Bs[cur][(wc * 64 + n * 16 + ar) * 32 + kg * 8]);
#pragma unroll
        for (int m = 0; m < 2; ++m)
#pragma unroll
            for (int n = 0; n < 4; ++n)
                acc[m][n] = __builtin_amdgcn_mfma_f32_16x16x32_bf16(a[m], b[n], acc[m][n], 0, 0, 0);
        if (ks < 15) __syncthreads();
    }
#undef STAGE_GP

    int rbase = kg * 4;
#pragma unroll
    for (int m = 0; m < 2; ++m) {
        int row = i0 + wr * 32 + m * 16 + rbase;
#pragma unroll
        for (int n = 0; n < 4; ++n) {
            int col = j0 + wc * 64 + n * 16 + ar;
#pragma unroll
            for (int r = 0; r < 4; ++r)
                gpre[(size_t)(row + r) * 2048 + col] = acc[m][n][r];
        }
    }
}

// ---------------------------------------------------------------------------
// per-step h-projections with IN-BLOCK k-split reduction (r17):
// block = output slice, its 4 waves = the 4 K-splits, LDS-reduced to FINAL
// outputs. dpartf[32][512] includes dec_b; ghh[32][2048] fully summed.
//   blocks 0..15 : dpartf slice (rg 0..1, cg 0..7),  16r x 64c
//   blocks 16..79: ghh   slice (rg 0..1, cg 0..31), 16r x 64c
// ---------------------------------------------------------------------------
__global__ __launch_bounds__(256) void k_hproj(const u16* __restrict__ hbf,
                                               const u16* __restrict__ decWbf,
                                               const u16* __restrict__ Whhbf,
                                               const float* __restrict__ dec_b,
                                               float* __restrict__ dpartf,
                                               float* __restrict__ ghh) {
    int tid = threadIdx.x, lane = tid & 63, ksw = tid >> 6;   // wave = k-split
    int ar = lane & 15, kg = lane >> 4, koff = kg * 8;
    __shared__ float red[4][16][64];   // 16 KB partials
    if (blockIdx.x < 16) {
        int rg = blockIdx.x >> 3, cg = blockIdx.x & 7;
        const u16* Arow = hbf + (rg * 16 + ar) * HH + ksw * 128 + koff;
        f32x4 acc[4] = {};
#pragma unroll
        for (int s = 0; s < 4; ++s) {
            int k0 = s * 32;
            bf8 a = *(const bf8*)(Arow + k0);
#pragma unroll
            for (int jt = 0; jt < 4; ++jt) {
                bf8 b = *(const bf8*)(decWbf + (cg * 64 + jt * 16 + ar) * HH + ksw * 128 + k0 + koff);
                acc[jt] = __builtin_amdgcn_mfma_f32_16x16x32_bf16(a, b, acc[jt], 0, 0, 0);
            }
        }
#pragma unroll
        for (int jt = 0; jt < 4; ++jt)
#pragma unroll
            for (int r = 0; r < 4; ++r)
                red[ksw][kg * 4 + r][jt * 16 + ar] = acc[jt][r];
        __syncthreads();
#pragma unroll
        for (int u = 0; u < 4; ++u) {
            int e = u * 256 + tid, r = e >> 6, c = e & 63;
            float s = ((red[0][r][c] + red[1][r][c]) + red[2][r][c]) + red[3][r][c];
            dpartf[(size_t)(rg * 16 + r) * AA + cg * 64 + c] = s + dec_b[cg * 64 + c];
        }
    } else {
        int d = blockIdx.x - 16, rg = d >> 5, cg = d & 31;
        const u16* Arow = hbf + (rg * 16 + ar) * HH + ksw * 128 + koff;
        f32x4 acc[4] = {};
#pragma unroll
        for (int s = 0; s < 4; ++s) {
            int k0 = s * 32;
            bf8 a = *(const bf8*)(Arow + k0);
#pragma unroll
            for (int jt = 0; jt < 4; ++jt) {
                bf8 b = *(const bf8*)(Whhbf + (size_t)(cg * 64 + jt * 16 + ar) * HH + ksw * 128 + k0 + koff);
                acc[jt] = __builtin_amdgcn_mfma_f32_16x16x32_bf16(a, b, acc[jt], 0, 0, 0);
            }
        }
#pragma unroll
        for (int jt = 0; jt < 4; ++jt)
#pragma unroll
            for (int r = 0; r < 4; ++r)
                red[ksw][kg * 4 + r][jt * 16 + ar] = acc[jt][r];
        __syncthreads();
#pragma unroll
        for (int u = 0; u < 4; ++u) {
            int e = u * 256 + tid, r = e >> 6, c = e & 63;
            float s = ((red[0][r][c] + red[1][r][c]) + red[2][r][c]) + red[3][r][c];
            ghh[(size_t)(rg * 16 + r) * 2048 + cg * 64 + c] = s;
        }
    }
}

// ---------------------------------------------------------------------------
// attexp[b,p] = exp(att_b + sum_a att_W[a]*tanh(enc_proj[b,p,a]+dpartf[b,a]))
// dpartf is pre-reduced (incl. dec_b) -> ONE dependent load stream.
// ---------------------------------------------------------------------------
__global__ __launch_bounds__(256) void k_attexp(const u16* __restrict__ encprojbf,
                                                const float* __restrict__ dpartf,
                                                const float* __restrict__ att_W,
                                                const float* __restrict__ att_b,
                                                float* __restrict__ attb) {
    int tid = threadIdx.x, lane = tid & 63;
    int row = blockIdx.x * 4 + (tid >> 6);
    int b = row / NP;
    bf8 x = *(const bf8*)(encprojbf + (size_t)row * AA + lane * 8);
    const f32x4* dp = (const f32x4*)(dpartf + (size_t)b * AA);
    const f32x4* aw = (const f32x4*)att_W;
    int ixA = lane * 2, ixB = lane * 2 + 1;
    f32x4 dA = dp[ixA], dB = dp[ixB];
    f32x4 wA = aw[ixA], wB = aw[ixB];
    float s = 0.f;
#pragma unroll
    for (int q = 0; q < 4; ++q) s += tanhf(bf2f((u16)x[q]) + dA[q]) * wA[q];
#pragma unroll
    for (int q = 0; q < 4; ++q) s += tanhf(bf2f((u16)x[4 + q]) + dB[q]) * wB[q];
#pragma unroll
    for (int off = 32; off > 0; off >>= 1) s += __shfl_down(s, off, 64);
    if (lane == 0) attb[row] = expf(s + att_b[0]);
}

// ---------------------------------------------------------------------------
// FUSED context-gate + LSTM cell, 1024 threads (r13). Block (b,u) owns cols
// {q*512 + u*64 + l}; thread = (pg<4, q<4, l<64), 49 p-iters each; wave reads
// ONE contiguous 128 B segment per p. ghh is pre-reduced (r17): 1 load.
// ---------------------------------------------------------------------------
__global__ __launch_bounds__(1024) void k_ctxgcell(const float* __restrict__ attb,
                                                   const u16* __restrict__ XWbf,
                                                   const float* __restrict__ gpre,
                                                   const float* __restrict__ ghh,
                                                   const float* __restrict__ b_ih,
                                                   const float* __restrict__ b_hh,
                                                   float* __restrict__ cbuf,
                                                   u16* __restrict__ hbf,
                                                   u16* __restrict__ hallbf, int t) {
    int b = blockIdx.x >> 3, u = blockIdx.x & 7;
    int tid = threadIdx.x;
    __shared__ float sa[NP];
    __shared__ float sred[4][4][64];
    __shared__ float sg[4][64];
    __shared__ float ssum;
    if (tid < NP) sa[tid] = attb[b * NP + tid];
    __syncthreads();
    if (tid < 64) {
        float s = 0.f;
        for (int p = tid; p < NP; p += 64) s += sa[p];
#pragma unroll
        for (int off = 32; off > 0; off >>= 1) s += __shfl_down(s, off, 64);
        if (tid == 0) ssum = s;
    }
    __syncthreads();
    float inv = 1.f / ssum;
    int l = tid & 63, q = (tid >> 6) & 3, pg = tid >> 8;   // tid = pg*256+q*64+l
    int gc = q * 512 + u * 64 + l;
    const u16* e = XWbf + (size_t)(b * NP + pg * 49) * 2048 + gc;
    float acc = 0.f;
#pragma unroll 7
    for (int p = 0; p < 49; ++p) acc += sa[pg * 49 + p] * bf2f(e[(size_t)p * 2048]);
    sred[pg][q][l] = acc;
    __syncthreads();
    if (tid < 256) {
        int q2 = tid >> 6, l2 = tid & 63;
        int gc2 = q2 * 512 + u * 64 + l2;
        float s = (sred[0][q2][l2] + sred[1][q2][l2] + sred[2][q2][l2]
                   + sred[3][q2][l2]) * inv
                + b_ih[gc2] + b_hh[gc2]
                + gpre[((size_t)b * 20 + t) * 2048 + gc2]
                + ghh[(size_t)b * 2048 + gc2];
        sg[q2][l2] = s;
    }
    __syncthreads();
    if (tid < 64) {
        int j = u * 64 + tid;
        float gi = sg[0][tid], gf = sg[1][tid], gg = sg[2][tid], go = sg[3][tid];
        float si = 1.f / (1.f + expf(-gi));
        float sf = 1.f / (1.f + expf(-gf));
        float so = 1.f / (1.f + expf(-go));
        float c2 = sf * cbuf[b * 512 + j] + si * tanhf(gg);
        cbuf[b * 512 + j] = c2;
        u16 hb = f2bf(so * tanhf(c2));
        hbf[b * 512 + j] = hb;
        hallbf[(b * 20 + t) * 512 + j] = hb;
    }
}

// ---------------------------------------------------------------------------
// logits (batched over all t): hall(640x512) @ fc_W^T(512x10000) + fc_b
// ---------------------------------------------------------------------------
__global__ __launch_bounds__(256) void k_logits(const u16* __restrict__ hallbf,
                                                const u16* __restrict__ fcWbf,
                                                const float* __restrict__ fc_b,
                                                float* __restrict__ out) {
    __shared__ u16 As[2][128 * 32];
    __shared__ u16 Bs[2][128 * 32];
    int tid = threadIdx.x, lane = tid & 63, w = tid >> 6;
    int wr = w >> 1, wc = w & 1;
    int i0 = blockIdx.x * 128, j0 = blockIdx.y * 128;
    int ar = lane & 15, kg = lane >> 4;

    int srow = tid >> 2;                 // 0..63
    int sc = (tid & 3) * 8;              // u16 col within 32
    int brow0 = min(j0 + srow, NV - 1);        // clamp: keep reads in-bounds
    int brow1 = min(j0 + 64 + srow, NV - 1);
    const u16* gA0 = hallbf + (size_t)(i0 + srow) * HH + sc;
    const u16* gA1 = hallbf + (size_t)(i0 + 64 + srow) * HH + sc;
    const u16* gB0 = fcWbf + (size_t)brow0 * HH + sc;
    const u16* gB1 = fcWbf + (size_t)brow1 * HH + sc;

    f32x4 acc[4][4] = {};

#define STAGE_LG(buf, k0)                                   \
    do {                                                    \
        gld16(gA0 + (k0), &As[buf][tid * 8]);               \
        gld16(gA1 + (k0), &As[buf][2048 + tid * 8]);        \
        gld16(gB0 + (k0), &Bs[buf][tid * 8]);               \
        gld16(gB1 + (k0), &Bs[buf][2048 + tid * 8]);        \
    } while (0)

    STAGE_LG(0, 0);
    __syncthreads();
    for (int ks = 0; ks < 16; ++ks) {
        int cur = ks & 1;
        if (ks < 15) STAGE_LG(cur ^ 1, (ks + 1) * 32);
        bf8 a[4], b[4];
#pragma unroll
        for (int m = 0; m < 4; ++m)
            a[m] = *(const bf8*)(&As[cur][(wr * 64 + m * 16 + ar) * 32 + kg * 8]);
#pragma unroll
        for (int n = 0; n < 4; ++n)
            b[n] = *(const bf8*)(&Bs[cur][(wc * 64 + n * 16 + ar) * 32 + kg * 8]);
#pragma unroll
        for (int m = 0; m < 4; ++m)
#pragma unroll
            for (int n = 0; n < 4; ++n)
                acc[m][n] = __builtin_amdgcn_mfma_f32_16x16x32_bf16(a[m], b[n], acc[m][n], 0, 0, 0);
        if (ks < 15) __syncthreads();
    }
#undef STAGE_LG

    int rbase = kg * 4;
#pragma unroll
    for (int m = 0; m < 4; ++m) {
        int row = i0 + wr * 64 + m * 16 + rbase;
#pragma unroll
        for (int n = 0; n < 4; ++n) {
            int col = j0 + wc * 64 + n * 16 + ar;
            if (col < NV) {
                float bias = fc_b[col];
#pragma unroll
                for (int r = 0; r < 4; ++r)
                    out[(size_t)(row + r) * NV + col] = acc[m][n][r] + bias;
            }
        }
    }
}

// ---------------------------------------------------------------------------
extern "C" void kernel_launch(void* const* d_in, const int* in_sizes, int n_in,
                              void* d_out, int out_size, void* d_ws, size_t ws_size,
                              hipStream_t stream) {
    (void)in_sizes; (void)n_in; (void)out_size; (void)ws_size;
    const float* enc   = (const float*)d_in[0];
    const int*   caps  = (const int*)d_in[1];
    const float* emb   = (const float*)d_in[2];
    const float* enc_W = (const float*)d_in[3];
    const float* enc_b = (const float*)d_in[4];
    const float* dec_W = (const float*)d_in[5];
    const float* dec_b = (const float*)d_in[6];
    const float* att_W = (const float*)d_in[7];
    const float* att_b = (const float*)d_in[8];
    const float* W_ih  = (const float*)d_in[9];
    const float* W_hh  = (const float*)d_in[10];
    const float* b_ih  = (const float*)d_in[11];
    const float* b_hh  = (const float*)d_in[12];
    const float* fc_W  = (const float*)d_in[13];
    const float* fc_b  = (const float*)d_in[14];
    float* out = (float*)d_out;

    char* base = (char*)d_ws;
    float* dpartf  = (float*)base;                 base += (size_t)32 * 512 * 4;
    float* attb    = (float*)base;                 base += (size_t)6272 * 4;
    float* cbuf    = (float*)base;                 base += (size_t)32 * 512 * 4;
    float* ghh     = (float*)base;                 base += (size_t)32 * 2048 * 4;
    float* gpre    = (float*)base;                 base += (size_t)640 * 2048 * 4;
    u16* encprojbf = (u16*)base;                   base += (size_t)6272 * 512 * 2;
    u16* Xbf    = (u16*)base;                      base += (size_t)32 * 196 * 2048 * 2;
    u16* Wencbf = (u16*)base;                      base += (size_t)512 * 2048 * 2;
    u16* decWbf = (u16*)base;                      base += (size_t)512 * 512 * 2;
    u16* Wihbf  = (u16*)base;                      base += (size_t)2048 * 2560 * 2;
    u16* Whhbf  = (u16*)base;                      base += (size_t)2048 * 512 * 2;
    u16* fcWbf  = (u16*)base;                      base += (size_t)10000 * 512 * 2;
    u16* embg   = (u16*)base;                      base += (size_t)32 * 20 * 512 * 2;
    u16* XWbf   = (u16*)base;                      base += (size_t)6272 * 2048 * 2;
    u16* hbf    = (u16*)base;                      base += (size_t)32 * 512 * 2;
    u16* hallbf = (u16*)base;                      base += (size_t)32 * 20 * 512 * 2;

    k_convert<<<3165, 256, 0, stream>>>(enc, enc_W, dec_W, W_ih, W_hh, fc_W, emb, caps,
                                        Xbf, Wencbf, decWbf, Wihbf, Whhbf, fcWbf,
                                        embg, cbuf, hbf);
    k_encxw<<<dim3(49, 20), 256, 0, stream>>>(Xbf, Wencbf, Wihbf, enc_b,
                                              encprojbf, XWbf);
    k_gpre<<<dim3(10, 16), 256, 0, stream>>>(embg, Wihbf, gpre);
    for (int t = 0; t < NT; ++t) {
        k_hproj<<<80, 256, 0, stream>>>(hbf, decWbf, Whhbf, dec_b, dpartf, ghh);
        k_attexp<<<1568, 256, 0, stream>>>(encprojbf, dpartf, att_W, att_b, attb);
        k_ctxgcell<<<256, 1024, 0, stream>>>(attb, XWbf, gpre, ghh, b_ih, b_hh,
                                             cbuf, hbf, hallbf, t);
    }
    k_logits<<<dim3(5, 79), 256, 0, stream>>>(hallbf, fcWbf, fc_b, out);
}

// Round 19
// 461.305 us; speedup vs baseline: 1.0732x; 1.0732x over previous
//
#include <hip/hip_runtime.h>
#include <math.h>

typedef unsigned short u16;
typedef __attribute__((ext_vector_type(8))) short bf8;    // 8 bf16 in 4 VGPRs
typedef __attribute__((ext_vector_type(8))) unsigned short u16x8;
typedef __attribute__((ext_vector_type(4))) float f32x4;

constexpr int NB = 32;      // batch
constexpr int NP = 196;     // pixels
constexpr int NE = 2048;    // encoder dim
constexpr int ED = 512;     // embedding dim
constexpr int HH = 512;     // hidden
constexpr int AA = 512;     // attention dim
constexpr int NV = 10000;   // vocab
constexpr int NT = 20;      // timesteps

__device__ inline u16 f2bf(float f) {
    unsigned u = __builtin_bit_cast(unsigned, f);
    u += 0x7fffu + ((u >> 16) & 1u);          // RNE
    return (u16)(u >> 16);
}
__device__ inline float bf2f(u16 h) {
    return __builtin_bit_cast(float, (unsigned)h << 16);
}
// nontemporal loads: the f32 inputs are single-use streams; keep them out of
// L2/L3 so the (reused) bf16 outputs stay cached.
// r18 lesson: 8 elems/thread + 12660 blocks is the measured optimum; the
// 32-elem/thread variant (3165 blocks) LOST 35 us (grid-level parallelism
// collapse). Convert's ~2.5 TB/s plateau is accepted; do not re-attempt.
__device__ inline void cvt8(const float* __restrict__ s, u16* __restrict__ d) {
    f32x4 v0 = __builtin_nontemporal_load((const f32x4*)s);
    f32x4 v1 = __builtin_nontemporal_load((const f32x4*)(s + 4));
    u16x8 o;
    o[0] = f2bf(v0[0]); o[1] = f2bf(v0[1]); o[2] = f2bf(v0[2]); o[3] = f2bf(v0[3]);
    o[4] = f2bf(v1[0]); o[5] = f2bf(v1[1]); o[6] = f2bf(v1[2]); o[7] = f2bf(v1[3]);
    *(u16x8*)d = o;
}

// async global->LDS, 16 bytes per lane (global_load_lds_dwordx4)
__device__ inline void gld16(const u16* g, u16* l) {
    __builtin_amdgcn_global_load_lds(
        (const __attribute__((address_space(1))) void*)g,
        (__attribute__((address_space(3))) void*)l, 16, 0, 0);
}

// ---------------------------------------------------------------------------
// one-shot: convert X + all weights to bf16 (8 elems/thread), gather
// embeddings, zero c and h.
// ---------------------------------------------------------------------------
__global__ void k_convert(const float* __restrict__ enc, const float* __restrict__ enc_W,
                          const float* __restrict__ dec_W, const float* __restrict__ W_ih,
                          const float* __restrict__ W_hh, const float* __restrict__ fc_W,
                          const float* __restrict__ emb, const int* __restrict__ caps,
                          u16* __restrict__ Xbf, u16* __restrict__ Wencbf,
                          u16* __restrict__ decWbf, u16* __restrict__ Wihbf,
                          u16* __restrict__ Whhbf, u16* __restrict__ fcWbf,
                          u16* __restrict__ embg, float* __restrict__ cbuf,
                          u16* __restrict__ hbf) {
    long g = (long)blockIdx.x * 256 + threadIdx.x;   // 8-element groups
    if (g < 1605632) { cvt8(enc + g * 8, Xbf + g * 8); return; }
    g -= 1605632;
    if (g < 131072) { cvt8(enc_W + g * 8, Wencbf + g * 8); return; }
    g -= 131072;
    if (g < 32768) { cvt8(dec_W + g * 8, decWbf + g * 8); return; }
    g -= 32768;
    if (g < 655360) { cvt8(W_ih + g * 8, Wihbf + g * 8); return; }
    g -= 655360;
    if (g < 131072) { cvt8(W_hh + g * 8, Whhbf + g * 8); return; }
    g -= 131072;
    if (g < 640000) { cvt8(fc_W + g * 8, fcWbf + g * 8); return; }
    g -= 640000;
    if (g < 40960) {   // emb gather: embg[b][t][512]
        long w = g >> 6, e8 = (g & 63) * 8;
        long b = w / 20, t = w - b * 20;
        int tok = caps[b * 21 + t];
        cvt8(emb + (size_t)tok * 512 + e8, embg + (size_t)w * 512 + e8);
        return;
    }
    g -= 40960;
    if (g < 2048) {
        *(float4*)(cbuf + g * 8) = make_float4(0.f, 0.f, 0.f, 0.f);
        *(float4*)(cbuf + g * 8 + 4) = make_float4(0.f, 0.f, 0.f, 0.f);
        return;
    }
    g -= 2048;
    if (g < 2048) { u16x8 z = {}; *(u16x8*)(hbf + g * 8) = z; }
}

// ---------------------------------------------------------------------------
// MERGED front GEMM: [enc_proj | XW] = X(6272x2048) @ [enc_W ; Wctx]^T
// (N = 2560). m97 structure, 128x128 tile, grid (49,20) = 980 blocks.
// T1 XCD bijective swizzle (r10). Static LDS x2 unroll (r12).
// r16 lesson: counted-vmcnt graft on this 2-phase structure is NULL.
// ---------------------------------------------------------------------------
__global__ __launch_bounds__(256) void k_encxw(const u16* __restrict__ Xbf,
                                               const u16* __restrict__ Wencbf,
                                               const u16* __restrict__ Wihbf,
                                               const float* __restrict__ enc_b,
                                               u16* __restrict__ encprojbf,
                                               u16* __restrict__ XWbf) {
    __shared__ u16 As0[128 * 32], As1[128 * 32];
    __shared__ u16 Bs0[128 * 32], Bs1[128 * 32];
    int tid = threadIdx.x, lane = tid & 63, w = tid >> 6;
    int wr = w >> 1, wc = w & 1;

    // bijective XCD swizzle (nwg = 980 = 8*122 + 4)
    int old = blockIdx.y * 49 + blockIdx.x;
    int xcd = old & 7, off = old >> 3;
    int nid = (xcd < 4 ? xcd * 123 : 492 + (xcd - 4) * 122) + off;
    int i0 = (nid / 20) * 128, j0 = (nid % 20) * 128;

    int ar = lane & 15, kg = lane >> 4;

    int srow = tid >> 2;                 // 0..63
    int sc = (tid & 3) * 8;              // u16 col within 32
    const u16* gA0 = Xbf + (size_t)(i0 + srow) * NE + sc;
    const u16* gA1 = gA0 + (size_t)64 * NE;
    size_t bstr;
    const u16* gB0;
    if (j0 < 512) { bstr = 2048; gB0 = Wencbf + (size_t)(j0 + srow) * 2048 + sc; }
    else          { bstr = 2560; gB0 = Wihbf + (size_t)(j0 - 512 + srow) * 2560 + 512 + sc; }
    const u16* gB1 = gB0 + 64 * bstr;

    f32x4 acc[4][4] = {};

#define STAGE_EX(A_, B_, k0)                                \
    do {                                                    \
        gld16(gA0 + (k0), &A_[tid * 8]);                    \
        gld16(gA1 + (k0), &A_[2048 + tid * 8]);             \
        gld16(gB0 + (k0), &B_[tid * 8]);                    \
        gld16(gB1 + (k0), &B_[2048 + tid * 8]);             \
    } while (0)

#define COMPUTE_EX(A_, B_)                                                     \
    do {                                                                       \
        bf8 a[4], b[4];                                                        \
        _Pragma("unroll") for (int m = 0; m < 4; ++m)                          \
            a[m] = *(const bf8*)(&A_[(wr * 64 + m * 16 + ar) * 32 + kg * 8]);  \
        _Pragma("unroll") for (int n = 0; n < 4; ++n)                          \
            b[n] = *(const bf8*)(&B_[(wc * 64 + n * 16 + ar) * 32 + kg * 8]);  \
        _Pragma("unroll") for (int m = 0; m < 4; ++m)                          \
            _Pragma("unroll") for (int n = 0; n < 4; ++n)                      \
                acc[m][n] = __builtin_amdgcn_mfma_f32_16x16x32_bf16(           \
                    a[m], b[n], acc[m][n], 0, 0, 0);                           \
    } while (0)

    STAGE_EX(As0, Bs0, 0);
    __syncthreads();
    for (int ks = 0; ks < 64; ks += 2) {
        STAGE_EX(As1, Bs1, (ks + 1) * 32);
        COMPUTE_EX(As0, Bs0);
        __syncthreads();
        if (ks < 62) STAGE_EX(As0, Bs0, (ks + 2) * 32);
        COMPUTE_EX(As1, Bs1);
        if (ks < 62) __syncthreads();
    }
#undef STAGE_EX
#undef COMPUTE_EX

    int rbase = kg * 4;
    if (j0 < 512) {
#pragma unroll
        for (int m = 0; m < 4; ++m) {
            int row = i0 + wr * 64 + m * 16 + rbase;
#pragma unroll
            for (int n = 0; n < 4; ++n) {
                int col = j0 + wc * 64 + n * 16 + ar;
                float bias = enc_b[col];
#pragma unroll
                for (int r = 0; r < 4; ++r)
                    encprojbf[(size_t)(row + r) * AA + col] = f2bf(acc[m][n][r] + bias);
            }
        }
    } else {
#pragma unroll
        for (int m = 0; m < 4; ++m) {
            int row = i0 + wr * 64 + m * 16 + rbase;
#pragma unroll
            for (int n = 0; n < 4; ++n) {
                int col = j0 - 512 + wc * 64 + n * 16 + ar;
#pragma unroll
                for (int r = 0; r < 4; ++r)
                    XWbf[(size_t)(row + r) * 2048 + col] = f2bf(acc[m][n][r]);
            }
        }
    }
}

// ---------------------------------------------------------------------------
// gpre = embg(640x512) @ Wemb^T -> f32[640][2048], Wemb = W_ih[:, 0:512].
// ---------------------------------------------------------------------------
__global__ __launch_bounds__(256) void k_gpre(const u16* __restrict__ embg,
                                              const u16* __restrict__ Wihbf,
                                              float* __restrict__ gpre) {
    __shared__ u16 As[2][64 * 32];
    __shared__ u16 Bs[2][128 * 32];
    int tid = threadIdx.x, lane = tid & 63, w = tid >> 6;
    int wr = w >> 1, wc = w & 1;
    int i0 = blockIdx.x * 64, j0 = blockIdx.y * 128;
    int ar = lane & 15, kg = lane >> 4;

    int srow = tid >> 2;
    int sc = (tid & 3) * 8;
    const u16* gA  = embg + (size_t)(i0 + srow) * 512 + sc;
    const u16* gB0 = Wihbf + (size_t)(j0 + srow) * 2560 + sc;
    const u16* gB1 = Wihbf + (size_t)(j0 + 64 + srow) * 2560 + sc;

    f32x4 acc[2][4] = {};

#define STAGE_GP(buf, k0)                                   \
    do {                                                    \
        gld16(gA + (k0), &As[buf][tid * 8]);                \
        gld16(gB0 + (k0), &Bs[buf][tid * 8]);               \
        gld16(gB1 + (k0), &Bs[buf][2048 + tid * 8]);        \
    } while (0)

    STAGE_GP(0, 0);
    __syncthreads();
    for (int ks = 0; ks < 16; ++ks) {
        int cur = ks & 1;
        if (ks < 15) STAGE_GP(cur ^ 1, (ks + 1) * 32);
        bf8 a[2], b[4];
#pragma unroll
        for (int m = 0; m < 2; ++m)
            a[m] = *(const bf8*)(&As[cur][(wr * 32 + m * 16 + ar) * 32 + kg * 8]);
#pragma unroll
        for (int n = 0; n < 4; ++n)
            b[n] = *(const bf8*)(&Bs[cur][(wc * 64 + n * 16 + ar) * 32 + kg * 8]);
#pragma unroll
        for (int m = 0; m < 2; ++m)
#pragma unroll
            for (int n = 0; n < 4; ++n)
                acc[m][n] = __builtin_amdgcn_mfma_f32_16x16x32_bf16(a[m], b[n], acc[m][n], 0, 0, 0);
        if (ks < 15) __syncthreads();
    }
#undef STAGE_GP

    int rbase = kg * 4;
#pragma unroll
    for (int m = 0; m < 2; ++m) {
        int row = i0 + wr * 32 + m * 16 + rbase;
#pragma unroll
        for (int n = 0; n < 4; ++n) {
            int col = j0 + wc * 64 + n * 16 + ar;
#pragma unroll
            for (int r = 0; r < 4; ++r)
                gpre[(size_t)(row + r) * 2048 + col] = acc[m][n][r];
        }
    }
}

// ---------------------------------------------------------------------------
// per-step h-projections with IN-BLOCK k-split reduction (r17):
// block = output slice, its 4 waves = the 4 K-splits, LDS-reduced to FINAL
// outputs. dpartf[32][512] includes dec_b; ghh[32][2048] fully summed.
//   blocks 0..15 : dpartf slice (rg 0..1, cg 0..7),  16r x 64c
//   blocks 16..79: ghh   slice (rg 0..1, cg 0..31), 16r x 64c
// ---------------------------------------------------------------------------
__global__ __launch_bounds__(256) void k_hproj(const u16* __restrict__ hbf,
                                               const u16* __restrict__ decWbf,
                                               const u16* __restrict__ Whhbf,
                                               const float* __restrict__ dec_b,
                                               float* __restrict__ dpartf,
                                               float* __restrict__ ghh) {
    int tid = threadIdx.x, lane = tid & 63, ksw = tid >> 6;   // wave = k-split
    int ar = lane & 15, kg = lane >> 4, koff = kg * 8;
    __shared__ float red[4][16][64];   // 16 KB partials
    if (blockIdx.x < 16) {
        int rg = blockIdx.x >> 3, cg = blockIdx.x & 7;
        const u16* Arow = hbf + (rg * 16 + ar) * HH + ksw * 128 + koff;
        f32x4 acc[4] = {};
#pragma unroll
        for (int s = 0; s < 4; ++s) {
            int k0 = s * 32;
            bf8 a = *(const bf8*)(Arow + k0);
#pragma unroll
            for (int jt = 0; jt < 4; ++jt) {
                bf8 b = *(const bf8*)(decWbf + (cg * 64 + jt * 16 + ar) * HH + ksw * 128 + k0 + koff);
                acc[jt] = __builtin_amdgcn_mfma_f32_16x16x32_bf16(a, b, acc[jt], 0, 0, 0);
            }
        }
#pragma unroll
        for (int jt = 0; jt < 4; ++jt)
#pragma unroll
            for (int r = 0; r < 4; ++r)
                red[ksw][kg * 4 + r][jt * 16 + ar] = acc[jt][r];
        __syncthreads();
#pragma unroll
        for (int u = 0; u < 4; ++u) {
            int e = u * 256 + tid, r = e >> 6, c = e & 63;
            float s = ((red[0][r][c] + red[1][r][c]) + red[2][r][c]) + red[3][r][c];
            dpartf[(size_t)(rg * 16 + r) * AA + cg * 64 + c] = s + dec_b[cg * 64 + c];
        }
    } else {
        int d = blockIdx.x - 16, rg = d >> 5, cg = d & 31;
        const u16* Arow = hbf + (rg * 16 + ar) * HH + ksw * 128 + koff;
        f32x4 acc[4] = {};
#pragma unroll
        for (int s = 0; s < 4; ++s) {
            int k0 = s * 32;
            bf8 a = *(const bf8*)(Arow + k0);
#pragma unroll
            for (int jt = 0; jt < 4; ++jt) {
                bf8 b = *(const bf8*)(Whhbf + (size_t)(cg * 64 + jt * 16 + ar) * HH + ksw * 128 + k0 + koff);
                acc[jt] = __builtin_amdgcn_mfma_f32_16x16x32_bf16(a, b, acc[jt], 0, 0, 0);
            }
        }
#pragma unroll
        for (int jt = 0; jt < 4; ++jt)
#pragma unroll
            for (int r = 0; r < 4; ++r)
                red[ksw][kg * 4 + r][jt * 16 + ar] = acc[jt][r];
        __syncthreads();
#pragma unroll
        for (int u = 0; u < 4; ++u) {
            int e = u * 256 + tid, r = e >> 6, c = e & 63;
            float s = ((red[0][r][c] + red[1][r][c]) + red[2][r][c]) + red[3][r][c];
            ghh[(size_t)(rg * 16 + r) * 2048 + cg * 64 + c] = s;
        }
    }
}

// ---------------------------------------------------------------------------
// attexp[b,p] = exp(att_b + sum_a att_W[a]*tanh(enc_proj[b,p,a]+dpartf[b,a]))
// dpartf is pre-reduced (incl. dec_b) -> ONE dependent load stream.
// ---------------------------------------------------------------------------
__global__ __launch_bounds__(256) void k_attexp(const u16* __restrict__ encprojbf,
                                                const float* __restrict__ dpartf,
                                                const float* __restrict__ att_W,
                                                const float* __restrict__ att_b,
                                                float* __restrict__ attb) {
    int tid = threadIdx.x, lane = tid & 63;
    int row = blockIdx.x * 4 + (tid >> 6);
    int b = row / NP;
    bf8 x = *(const bf8*)(encprojbf + (size_t)row * AA + lane * 8);
    const f32x4* dp = (const f32x4*)(dpartf + (size_t)b * AA);
    const f32x4* aw = (const f32x4*)att_W;
    int ixA = lane * 2, ixB = lane * 2 + 1;
    f32x4 dA = dp[ixA], dB = dp[ixB];
    f32x4 wA = aw[ixA], wB = aw[ixB];
    float s = 0.f;
#pragma unroll
    for (int q = 0; q < 4; ++q) s += tanhf(bf2f((u16)x[q]) + dA[q]) * wA[q];
#pragma unroll
    for (int q = 0; q < 4; ++q) s += tanhf(bf2f((u16)x[4 + q]) + dB[q]) * wB[q];
#pragma unroll
    for (int off = 32; off > 0; off >>= 1) s += __shfl_down(s, off, 64);
    if (lane == 0) attb[row] = expf(s + att_b[0]);
}

// ---------------------------------------------------------------------------
// FUSED context-gate + LSTM cell, 1024 threads (r13). Block (b,u) owns cols
// {q*512 + u*64 + l}; thread = (pg<4, q<4, l<64), 49 p-iters each; wave reads
// ONE contiguous 128 B segment per p. ghh is pre-reduced (r17): 1 load.
// ---------------------------------------------------------------------------
__global__ __launch_bounds__(1024) void k_ctxgcell(const float* __restrict__ attb,
                                                   const u16* __restrict__ XWbf,
                                                   const float* __restrict__ gpre,
                                                   const float* __restrict__ ghh,
                                                   const float* __restrict__ b_ih,
                                                   const float* __restrict__ b_hh,
                                                   float* __restrict__ cbuf,
                                                   u16* __restrict__ hbf,
                                                   u16* __restrict__ hallbf, int t) {
    int b = blockIdx.x >> 3, u = blockIdx.x & 7;
    int tid = threadIdx.x;
    __shared__ float sa[NP];
    __shared__ float sred[4][4][64];
    __shared__ float sg[4][64];
    __shared__ float ssum;
    if (tid < NP) sa[tid] = attb[b * NP + tid];
    __syncthreads();
    if (tid < 64) {
        float s = 0.f;
        for (int p = tid; p < NP; p += 64) s += sa[p];
#pragma unroll
        for (int off = 32; off > 0; off >>= 1) s += __shfl_down(s, off, 64);
        if (tid == 0) ssum = s;
    }
    __syncthreads();
    float inv = 1.f / ssum;
    int l = tid & 63, q = (tid >> 6) & 3, pg = tid >> 8;   // tid = pg*256+q*64+l
    int gc = q * 512 + u * 64 + l;
    const u16* e = XWbf + (size_t)(b * NP + pg * 49) * 2048 + gc;
    float acc = 0.f;
#pragma unroll 7
    for (int p = 0; p < 49; ++p) acc += sa[pg * 49 + p] * bf2f(e[(size_t)p * 2048]);
    sred[pg][q][l] = acc;
    __syncthreads();
    if (tid < 256) {
        int q2 = tid >> 6, l2 = tid & 63;
        int gc2 = q2 * 512 + u * 64 + l2;
        float s = (sred[0][q2][l2] + sred[1][q2][l2] + sred[2][q2][l2]
                   + sred[3][q2][l2]) * inv
                + b_ih[gc2] + b_hh[gc2]
                + gpre[((size_t)b * 20 + t) * 2048 + gc2]
                + ghh[(size_t)b * 2048 + gc2];
        sg[q2][l2] = s;
    }
    __syncthreads();
    if (tid < 64) {
        int j = u * 64 + tid;
        float gi = sg[0][tid], gf = sg[1][tid], gg = sg[2][tid], go = sg[3][tid];
        float si = 1.f / (1.f + expf(-gi));
        float sf = 1.f / (1.f + expf(-gf));
        float so = 1.f / (1.f + expf(-go));
        float c2 = sf * cbuf[b * 512 + j] + si * tanhf(gg);
        cbuf[b * 512 + j] = c2;
        u16 hb = f2bf(so * tanhf(c2));
        hbf[b * 512 + j] = hb;
        hallbf[(b * 20 + t) * 512 + j] = hb;
    }
}

// ---------------------------------------------------------------------------
// logits (batched over all t): hall(640x512) @ fc_W^T(512x10000) + fc_b
// ---------------------------------------------------------------------------
__global__ __launch_bounds__(256) void k_logits(const u16* __restrict__ hallbf,
                                                const u16* __restrict__ fcWbf,
                                                const float* __restrict__ fc_b,
                                                float* __restrict__ out) {
    __shared__ u16 As[2][128 * 32];
    __shared__ u16 Bs[2][128 * 32];
    int tid = threadIdx.x, lane = tid & 63, w = tid >> 6;
    int wr = w >> 1, wc = w & 1;
    int i0 = blockIdx.x * 128, j0 = blockIdx.y * 128;
    int ar = lane & 15, kg = lane >> 4;

    int srow = tid >> 2;                 // 0..63
    int sc = (tid & 3) * 8;              // u16 col within 32
    int brow0 = min(j0 + srow, NV - 1);        // clamp: keep reads in-bounds
    int brow1 = min(j0 + 64 + srow, NV - 1);
    const u16* gA0 = hallbf + (size_t)(i0 + srow) * HH + sc;
    const u16* gA1 = hallbf + (size_t)(i0 + 64 + srow) * HH + sc;
    const u16* gB0 = fcWbf + (size_t)brow0 * HH + sc;
    const u16* gB1 = fcWbf + (size_t)brow1 * HH + sc;

    f32x4 acc[4][4] = {};

#define STAGE_LG(buf, k0)                                   \
    do {                                                    \
        gld16(gA0 + (k0), &As[buf][tid * 8]);               \
        gld16(gA1 + (k0), &As[buf][2048 + tid * 8]);        \
        gld16(gB0 + (k0), &Bs[buf][tid * 8]);               \
        gld16(gB1 + (k0), &Bs[buf][2048 + tid * 8]);        \
    } while (0)

    STAGE_LG(0, 0);
    __syncthreads();
    for (int ks = 0; ks < 16; ++ks) {
        int cur = ks & 1;
        if (ks < 15) STAGE_LG(cur ^ 1, (ks + 1) * 32);
        bf8 a[4], b[4];
#pragma unroll
        for (int m = 0; m < 4; ++m)
            a[m] = *(const bf8*)(&As[cur][(wr * 64 + m * 16 + ar) * 32 + kg * 8]);
#pragma unroll
        for (int n = 0; n < 4; ++n)
            b[n] = *(const bf8*)(&Bs[cur][(wc * 64 + n * 16 + ar) * 32 + kg * 8]);
#pragma unroll
        for (int m = 0; m < 4; ++m)
#pragma unroll
            for (int n = 0; n < 4; ++n)
                acc[m][n] = __builtin_amdgcn_mfma_f32_16x16x32_bf16(a[m], b[n], acc[m][n], 0, 0, 0);
        if (ks < 15) __syncthreads();
    }
#undef STAGE_LG

    int rbase = kg * 4;
#pragma unroll
    for (int m = 0; m < 4; ++m) {
        int row = i0 + wr * 64 + m * 16 + rbase;
#pragma unroll
        for (int n = 0; n < 4; ++n) {
            int col = j0 + wc * 64 + n * 16 + ar;
            if (col < NV) {
                float bias = fc_b[col];
#pragma unroll
                for (int r = 0; r < 4; ++r)
                    out[(size_t)(row + r) * NV + col] = acc[m][n][r] + bias;
            }
        }
    }
}

// ---------------------------------------------------------------------------
extern "C" void kernel_launch(void* const* d_in, const int* in_sizes, int n_in,
                              void* d_out, int out_size, void* d_ws, size_t ws_size,
                              hipStream_t stream) {
    (void)in_sizes; (void)n_in; (void)out_size; (void)ws_size;
    const float* enc   = (const float*)d_in[0];
    const int*   caps  = (const int*)d_in[1];
    const float* emb   = (const float*)d_in[2];
    const float* enc_W = (const float*)d_in[3];
    const float* enc_b = (const float*)d_in[4];
    const float* dec_W = (const float*)d_in[5];
    const float* dec_b = (const float*)d_in[6];
    const float* att_W = (const float*)d_in[7];
    const float* att_b = (const float*)d_in[8];
    const float* W_ih  = (const float*)d_in[9];
    const float* W_hh  = (const float*)d_in[10];
    const float* b_ih  = (const float*)d_in[11];
    const float* b_hh  = (const float*)d_in[12];
    const float* fc_W  = (const float*)d_in[13];
    const float* fc_b  = (const float*)d_in[14];
    float* out = (float*)d_out;

    char* base = (char*)d_ws;
    float* dpartf  = (float*)base;                 base += (size_t)32 * 512 * 4;
    float* attb    = (float*)base;                 base += (size_t)6272 * 4;
    float* cbuf    = (float*)base;                 base += (size_t)32 * 512 * 4;
    float* ghh     = (float*)base;                 base += (size_t)32 * 2048 * 4;
    float* gpre    = (float*)base;                 base += (size_t)640 * 2048 * 4;
    u16* encprojbf = (u16*)base;                   base += (size_t)6272 * 512 * 2;
    u16* Xbf    = (u16*)base;                      base += (size_t)32 * 196 * 2048 * 2;
    u16* Wencbf = (u16*)base;                      base += (size_t)512 * 2048 * 2;
    u16* decWbf = (u16*)base;                      base += (size_t)512 * 512 * 2;
    u16* Wihbf  = (u16*)base;                      base += (size_t)2048 * 2560 * 2;
    u16* Whhbf  = (u16*)base;                      base += (size_t)2048 * 512 * 2;
    u16* fcWbf  = (u16*)base;                      base += (size_t)10000 * 512 * 2;
    u16* embg   = (u16*)base;                      base += (size_t)32 * 20 * 512 * 2;
    u16* XWbf   = (u16*)base;                      base += (size_t)6272 * 2048 * 2;
    u16* hbf    = (u16*)base;                      base += (size_t)32 * 512 * 2;
    u16* hallbf = (u16*)base;                      base += (size_t)32 * 20 * 512 * 2;

    k_convert<<<12660, 256, 0, stream>>>(enc, enc_W, dec_W, W_ih, W_hh, fc_W, emb, caps,
                                         Xbf, Wencbf, decWbf, Wihbf, Whhbf, fcWbf,
                                         embg, cbuf, hbf);
    k_encxw<<<dim3(49, 20), 256, 0, stream>>>(Xbf, Wencbf, Wihbf, enc_b,
                                              encprojbf, XWbf);
    k_gpre<<<dim3(10, 16), 256, 0, stream>>>(embg, Wihbf, gpre);
    for (int t = 0; t < NT; ++t) {
        k_hproj<<<80, 256, 0, stream>>>(hbf, decWbf, Whhbf, dec_b, dpartf, ghh);
        k_attexp<<<1568, 256, 0, stream>>>(encprojbf, dpartf, att_W, att_b, attb);
        k_ctxgcell<<<256, 1024, 0, stream>>>(attb, XWbf, gpre, ghh, b_ih, b_hh,
                                             cbuf, hbf, hallbf, t);
    }
    k_logits<<<dim3(5, 79), 256, 0, stream>>>(hallbf, fcWbf, fc_b, out);
}

// Round 20
// 454.665 us; speedup vs baseline: 1.0889x; 1.0146x over previous
//
#include <hip/hip_runtime.h>
#include <math.h>

typedef unsigned short u16;
typedef __attribute__((ext_vector_type(8))) short bf8;    // 8 bf16 in 4 VGPRs
typedef __attribute__((ext_vector_type(8))) unsigned short u16x8;
typedef __attribute__((ext_vector_type(4))) float f32x4;

constexpr int NB = 32;      // batch
constexpr int NP = 196;     // pixels
constexpr int NE = 2048;    // encoder dim
constexpr int ED = 512;     // embedding dim
constexpr int HH = 512;     // hidden
constexpr int AA = 512;     // attention dim
constexpr int NV = 10000;   // vocab
constexpr int NT = 20;      // timesteps

__device__ inline u16 f2bf(float f) {
    unsigned u = __builtin_bit_cast(unsigned, f);
    u += 0x7fffu + ((u >> 16) & 1u);          // RNE
    return (u16)(u >> 16);
}
__device__ inline float bf2f(u16 h) {
    return __builtin_bit_cast(float, (unsigned)h << 16);
}
// nontemporal loads: the f32 inputs are single-use streams.
// r18 lesson: 8 elems/thread + 12660 blocks is the measured optimum.
__device__ inline void cvt8(const float* __restrict__ s, u16* __restrict__ d) {
    f32x4 v0 = __builtin_nontemporal_load((const f32x4*)s);
    f32x4 v1 = __builtin_nontemporal_load((const f32x4*)(s + 4));
    u16x8 o;
    o[0] = f2bf(v0[0]); o[1] = f2bf(v0[1]); o[2] = f2bf(v0[2]); o[3] = f2bf(v0[3]);
    o[4] = f2bf(v1[0]); o[5] = f2bf(v1[1]); o[6] = f2bf(v1[2]); o[7] = f2bf(v1[3]);
    *(u16x8*)d = o;
}

// async global->LDS, 16 bytes per lane (global_load_lds_dwordx4)
__device__ inline void gld16(const u16* g, u16* l) {
    __builtin_amdgcn_global_load_lds(
        (const __attribute__((address_space(1))) void*)g,
        (__attribute__((address_space(3))) void*)l, 16, 0, 0);
}

// ---------------------------------------------------------------------------
// one-shot: convert X + all weights to bf16 (8 elems/thread), gather
// embeddings, zero c and h.
// ---------------------------------------------------------------------------
__global__ void k_convert(const float* __restrict__ enc, const float* __restrict__ enc_W,
                          const float* __restrict__ dec_W, const float* __restrict__ W_ih,
                          const float* __restrict__ W_hh, const float* __restrict__ fc_W,
                          const float* __restrict__ emb, const int* __restrict__ caps,
                          u16* __restrict__ Xbf, u16* __restrict__ Wencbf,
                          u16* __restrict__ decWbf, u16* __restrict__ Wihbf,
                          u16* __restrict__ Whhbf, u16* __restrict__ fcWbf,
                          u16* __restrict__ embg, float* __restrict__ cbuf,
                          u16* __restrict__ hbf) {
    long g = (long)blockIdx.x * 256 + threadIdx.x;   // 8-element groups
    if (g < 1605632) { cvt8(enc + g * 8, Xbf + g * 8); return; }
    g -= 1605632;
    if (g < 131072) { cvt8(enc_W + g * 8, Wencbf + g * 8); return; }
    g -= 131072;
    if (g < 32768) { cvt8(dec_W + g * 8, decWbf + g * 8); return; }
    g -= 32768;
    if (g < 655360) { cvt8(W_ih + g * 8, Wihbf + g * 8); return; }
    g -= 655360;
    if (g < 131072) { cvt8(W_hh + g * 8, Whhbf + g * 8); return; }
    g -= 131072;
    if (g < 640000) { cvt8(fc_W + g * 8, fcWbf + g * 8); return; }
    g -= 640000;
    if (g < 40960) {   // emb gather: embg[b][t][512]
        long w = g >> 6, e8 = (g & 63) * 8;
        long b = w / 20, t = w - b * 20;
        int tok = caps[b * 21 + t];
        cvt8(emb + (size_t)tok * 512 + e8, embg + (size_t)w * 512 + e8);
        return;
    }
    g -= 40960;
    if (g < 2048) {
        *(float4*)(cbuf + g * 8) = make_float4(0.f, 0.f, 0.f, 0.f);
        *(float4*)(cbuf + g * 8 + 4) = make_float4(0.f, 0.f, 0.f, 0.f);
        return;
    }
    g -= 2048;
    if (g < 2048) { u16x8 z = {}; *(u16x8*)(hbf + g * 8) = z; }
}

// ---------------------------------------------------------------------------
// MERGED front GEMM: [enc_proj | XW] = X(6272x2048) @ [enc_W ; Wctx]^T
// (N = 2560). m97 structure, 128x128 tile, grid (49,20) = 980 blocks.
// T1 XCD bijective swizzle (r10). Static LDS x2 unroll (r12).
// ---------------------------------------------------------------------------
__global__ __launch_bounds__(256) void k_encxw(const u16* __restrict__ Xbf,
                                               const u16* __restrict__ Wencbf,
                                               const u16* __restrict__ Wihbf,
                                               const float* __restrict__ enc_b,
                                               u16* __restrict__ encprojbf,
                                               u16* __restrict__ XWbf) {
    __shared__ u16 As0[128 * 32], As1[128 * 32];
    __shared__ u16 Bs0[128 * 32], Bs1[128 * 32];
    int tid = threadIdx.x, lane = tid & 63, w = tid >> 6;
    int wr = w >> 1, wc = w & 1;

    // bijective XCD swizzle (nwg = 980 = 8*122 + 4)
    int old = blockIdx.y * 49 + blockIdx.x;
    int xcd = old & 7, off = old >> 3;
    int nid = (xcd < 4 ? xcd * 123 : 492 + (xcd - 4) * 122) + off;
    int i0 = (nid / 20) * 128, j0 = (nid % 20) * 128;

    int ar = lane & 15, kg = lane >> 4;

    int srow = tid >> 2;                 // 0..63
    int sc = (tid & 3) * 8;              // u16 col within 32
    const u16* gA0 = Xbf + (size_t)(i0 + srow) * NE + sc;
    const u16* gA1 = gA0 + (size_t)64 * NE;
    size_t bstr;
    const u16* gB0;
    if (j0 < 512) { bstr = 2048; gB0 = Wencbf + (size_t)(j0 + srow) * 2048 + sc; }
    else          { bstr = 2560; gB0 = Wihbf + (size_t)(j0 - 512 + srow) * 2560 + 512 + sc; }
    const u16* gB1 = gB0 + 64 * bstr;

    f32x4 acc[4][4] = {};

#define STAGE_EX(A_, B_, k0)                                \
    do {                                                    \
        gld16(gA0 + (k0), &A_[tid * 8]);                    \
        gld16(gA1 + (k0), &A_[2048 + tid * 8]);             \
        gld16(gB0 + (k0), &B_[tid * 8]);                    \
        gld16(gB1 + (k0), &B_[2048 + tid * 8]);             \
    } while (0)

#define COMPUTE_EX(A_, B_)                                                     \
    do {                                                                       \
        bf8 a[4], b[4];                                                        \
        _Pragma("unroll") for (int m = 0; m < 4; ++m)                          \
            a[m] = *(const bf8*)(&A_[(wr * 64 + m * 16 + ar) * 32 + kg * 8]);  \
        _Pragma("unroll") for (int n = 0; n < 4; ++n)                          \
            b[n] = *(const bf8*)(&B_[(wc * 64 + n * 16 + ar) * 32 + kg * 8]);  \
        _Pragma("unroll") for (int m = 0; m < 4; ++m)                          \
            _Pragma("unroll") for (int n = 0; n < 4; ++n)                      \
                acc[m][n] = __builtin_amdgcn_mfma_f32_16x16x32_bf16(           \
                    a[m], b[n], acc[m][n], 0, 0, 0);                           \
    } while (0)

    STAGE_EX(As0, Bs0, 0);
    __syncthreads();
    for (int ks = 0; ks < 64; ks += 2) {
        STAGE_EX(As1, Bs1, (ks + 1) * 32);
        COMPUTE_EX(As0, Bs0);
        __syncthreads();
        if (ks < 62) STAGE_EX(As0, Bs0, (ks + 2) * 32);
        COMPUTE_EX(As1, Bs1);
        if (ks < 62) __syncthreads();
    }
#undef STAGE_EX
#undef COMPUTE_EX

    int rbase = kg * 4;
    if (j0 < 512) {
#pragma unroll
        for (int m = 0; m < 4; ++m) {
            int row = i0 + wr * 64 + m * 16 + rbase;
#pragma unroll
            for (int n = 0; n < 4; ++n) {
                int col = j0 + wc * 64 + n * 16 + ar;
                float bias = enc_b[col];
#pragma unroll
                for (int r = 0; r < 4; ++r)
                    encprojbf[(size_t)(row + r) * AA + col] = f2bf(acc[m][n][r] + bias);
            }
        }
    } else {
#pragma unroll
        for (int m = 0; m < 4; ++m) {
            int row = i0 + wr * 64 + m * 16 + rbase;
#pragma unroll
            for (int n = 0; n < 4; ++n) {
                int col = j0 - 512 + wc * 64 + n * 16 + ar;
#pragma unroll
                for (int r = 0; r < 4; ++r)
                    XWbf[(size_t)(row + r) * 2048 + col] = f2bf(acc[m][n][r]);
            }
        }
    }
}

// ---------------------------------------------------------------------------
// gpre = embg(640x512) @ Wemb^T -> f32[640][2048], Wemb = W_ih[:, 0:512].
// r20: static LDS buffers (r12 mechanism, proven on k_encxw).
// ---------------------------------------------------------------------------
__global__ __launch_bounds__(256) void k_gpre(const u16* __restrict__ embg,
                                              const u16* __restrict__ Wihbf,
                                              float* __restrict__ gpre) {
    __shared__ u16 As0[64 * 32], As1[64 * 32];
    __shared__ u16 Bs0[128 * 32], Bs1[128 * 32];
    int tid = threadIdx.x, lane = tid & 63, w = tid >> 6;
    int wr = w >> 1, wc = w & 1;
    int i0 = blockIdx.x * 64, j0 = blockIdx.y * 128;
    int ar = lane & 15, kg = lane >> 4;

    int srow = tid >> 2;
    int sc = (tid & 3) * 8;
    const u16* gA  = embg + (size_t)(i0 + srow) * 512 + sc;
    const u16* gB0 = Wihbf + (size_t)(j0 + srow) * 2560 + sc;
    const u16* gB1 = Wihbf + (size_t)(j0 + 64 + srow) * 2560 + sc;

    f32x4 acc[2][4] = {};

#define STAGE_GP(A_, B_, k0)                                \
    do {                                                    \
        gld16(gA + (k0), &A_[tid * 8]);                     \
        gld16(gB0 + (k0), &B_[tid * 8]);                    \
        gld16(gB1 + (k0), &B_[2048 + tid * 8]);             \
    } while (0)

#define COMPUTE_GP(A_, B_)                                                     \
    do {                                                                       \
        bf8 a[2], b[4];                                                        \
        _Pragma("unroll") for (int m = 0; m < 2; ++m)                          \
            a[m] = *(const bf8*)(&A_[(wr * 32 + m * 16 + ar) * 32 + kg * 8]);  \
        _Pragma("unroll") for (int n = 0; n < 4; ++n)                          \
            b[n] = *(const bf8*)(&B_[(wc * 64 + n * 16 + ar) * 32 + kg * 8]);  \
        _Pragma("unroll") for (int m = 0; m < 2; ++m)                          \
            _Pragma("unroll") for (int n = 0; n < 4; ++n)                      \
                acc[m][n] = __builtin_amdgcn_mfma_f32_16x16x32_bf16(           \
                    a[m], b[n], acc[m][n], 0, 0, 0);                           \
    } while (0)

    STAGE_GP(As0, Bs0, 0);
    __syncthreads();
    for (int ks = 0; ks < 16; ks += 2) {
        STAGE_GP(As1, Bs1, (ks + 1) * 32);
        COMPUTE_GP(As0, Bs0);
        __syncthreads();
        if (ks < 14) STAGE_GP(As0, Bs0, (ks + 2) * 32);
        COMPUTE_GP(As1, Bs1);
        if (ks < 14) __syncthreads();
    }
#undef STAGE_GP
#undef COMPUTE_GP

    int rbase = kg * 4;
#pragma unroll
    for (int m = 0; m < 2; ++m) {
        int row = i0 + wr * 32 + m * 16 + rbase;
#pragma unroll
        for (int n = 0; n < 4; ++n) {
            int col = j0 + wc * 64 + n * 16 + ar;
#pragma unroll
            for (int r = 0; r < 4; ++r)
                gpre[(size_t)(row + r) * 2048 + col] = acc[m][n][r];
        }
    }
}

// ---------------------------------------------------------------------------
// per-step h-projections with IN-BLOCK k-split reduction (r17):
// block = output slice, its 4 waves = the 4 K-splits, LDS-reduced to FINAL
// outputs. dpartf[32][512] includes dec_b; ghh[32][2048] fully summed.
//   blocks 0..15 : dpartf slice (rg 0..1, cg 0..7),  16r x 64c
//   blocks 16..79: ghh   slice (rg 0..1, cg 0..31), 16r x 64c
// ---------------------------------------------------------------------------
__global__ __launch_bounds__(256) void k_hproj(const u16* __restrict__ hbf,
                                               const u16* __restrict__ decWbf,
                                               const u16* __restrict__ Whhbf,
                                               const float* __restrict__ dec_b,
                                               float* __restrict__ dpartf,
                                               float* __restrict__ ghh) {
    int tid = threadIdx.x, lane = tid & 63, ksw = tid >> 6;   // wave = k-split
    int ar = lane & 15, kg = lane >> 4, koff = kg * 8;
    __shared__ float red[4][16][64];   // 16 KB partials
    if (blockIdx.x < 16) {
        int rg = blockIdx.x >> 3, cg = blockIdx.x & 7;
        const u16* Arow = hbf + (rg * 16 + ar) * HH + ksw * 128 + koff;
        f32x4 acc[4] = {};
#pragma unroll
        for (int s = 0; s < 4; ++s) {
            int k0 = s * 32;
            bf8 a = *(const bf8*)(Arow + k0);
#pragma unroll
            for (int jt = 0; jt < 4; ++jt) {
                bf8 b = *(const bf8*)(decWbf + (cg * 64 + jt * 16 + ar) * HH + ksw * 128 + k0 + koff);
                acc[jt] = __builtin_amdgcn_mfma_f32_16x16x32_bf16(a, b, acc[jt], 0, 0, 0);
            }
        }
#pragma unroll
        for (int jt = 0; jt < 4; ++jt)
#pragma unroll
            for (int r = 0; r < 4; ++r)
                red[ksw][kg * 4 + r][jt * 16 + ar] = acc[jt][r];
        __syncthreads();
#pragma unroll
        for (int u = 0; u < 4; ++u) {
            int e = u * 256 + tid, r = e >> 6, c = e & 63;
            float s = ((red[0][r][c] + red[1][r][c]) + red[2][r][c]) + red[3][r][c];
            dpartf[(size_t)(rg * 16 + r) * AA + cg * 64 + c] = s + dec_b[cg * 64 + c];
        }
    } else {
        int d = blockIdx.x - 16, rg = d >> 5, cg = d & 31;
        const u16* Arow = hbf + (rg * 16 + ar) * HH + ksw * 128 + koff;
        f32x4 acc[4] = {};
#pragma unroll
        for (int s = 0; s < 4; ++s) {
            int k0 = s * 32;
            bf8 a = *(const bf8*)(Arow + k0);
#pragma unroll
            for (int jt = 0; jt < 4; ++jt) {
                bf8 b = *(const bf8*)(Whhbf + (size_t)(cg * 64 + jt * 16 + ar) * HH + ksw * 128 + k0 + koff);
                acc[jt] = __builtin_amdgcn_mfma_f32_16x16x32_bf16(a, b, acc[jt], 0, 0, 0);
            }
        }
#pragma unroll
        for (int jt = 0; jt < 4; ++jt)
#pragma unroll
            for (int r = 0; r < 4; ++r)
                red[ksw][kg * 4 + r][jt * 16 + ar] = acc[jt][r];
        __syncthreads();
#pragma unroll
        for (int u = 0; u < 4; ++u) {
            int e = u * 256 + tid, r = e >> 6, c = e & 63;
            float s = ((red[0][r][c] + red[1][r][c]) + red[2][r][c]) + red[3][r][c];
            ghh[(size_t)(rg * 16 + r) * 2048 + cg * 64 + c] = s;
        }
    }
}

// ---------------------------------------------------------------------------
// attexp[b,p] = exp(att_b + sum_a att_W[a]*tanh(enc_proj[b,p,a]+dpartf[b,a]))
// dpartf is pre-reduced (incl. dec_b) -> ONE dependent load stream.
// ---------------------------------------------------------------------------
__global__ __launch_bounds__(256) void k_attexp(const u16* __restrict__ encprojbf,
                                                const float* __restrict__ dpartf,
                                                const float* __restrict__ att_W,
                                                const float* __restrict__ att_b,
                                                float* __restrict__ attb) {
    int tid = threadIdx.x, lane = tid & 63;
    int row = blockIdx.x * 4 + (tid >> 6);
    int b = row / NP;
    bf8 x = *(const bf8*)(encprojbf + (size_t)row * AA + lane * 8);
    const f32x4* dp = (const f32x4*)(dpartf + (size_t)b * AA);
    const f32x4* aw = (const f32x4*)att_W;
    int ixA = lane * 2, ixB = lane * 2 + 1;
    f32x4 dA = dp[ixA], dB = dp[ixB];
    f32x4 wA = aw[ixA], wB = aw[ixB];
    float s = 0.f;
#pragma unroll
    for (int q = 0; q < 4; ++q) s += tanhf(bf2f((u16)x[q]) + dA[q]) * wA[q];
#pragma unroll
    for (int q = 0; q < 4; ++q) s += tanhf(bf2f((u16)x[4 + q]) + dB[q]) * wB[q];
#pragma unroll
    for (int off = 32; off > 0; off >>= 1) s += __shfl_down(s, off, 64);
    if (lane == 0) attb[row] = expf(s + att_b[0]);
}

// ---------------------------------------------------------------------------
// FUSED context-gate + LSTM cell, 1024 threads (r13). Block (b,u) owns cols
// {q*512 + u*64 + l}; thread = (pg<4, q<4, l<64), 49 p-iters each; wave reads
// ONE contiguous 128 B segment per p. ghh is pre-reduced (r17): 1 load.
// ---------------------------------------------------------------------------
__global__ __launch_bounds__(1024) void k_ctxgcell(const float* __restrict__ attb,
                                                   const u16* __restrict__ XWbf,
                                                   const float* __restrict__ gpre,
                                                   const float* __restrict__ ghh,
                                                   const float* __restrict__ b_ih,
                                                   const float* __restrict__ b_hh,
                                                   float* __restrict__ cbuf,
                                                   u16* __restrict__ hbf,
                                                   u16* __restrict__ hallbf, int t) {
    int b = blockIdx.x >> 3, u = blockIdx.x & 7;
    int tid = threadIdx.x;
    __shared__ float sa[NP];
    __shared__ float sred[4][4][64];
    __shared__ float sg[4][64];
    __shared__ float ssum;
    if (tid < NP) sa[tid] = attb[b * NP + tid];
    __syncthreads();
    if (tid < 64) {
        float s = 0.f;
        for (int p = tid; p < NP; p += 64) s += sa[p];
#pragma unroll
        for (int off = 32; off > 0; off >>= 1) s += __shfl_down(s, off, 64);
        if (tid == 0) ssum = s;
    }
    __syncthreads();
    float inv = 1.f / ssum;
    int l = tid & 63, q = (tid >> 6) & 3, pg = tid >> 8;   // tid = pg*256+q*64+l
    int gc = q * 512 + u * 64 + l;
    const u16* e = XWbf + (size_t)(b * NP + pg * 49) * 2048 + gc;
    float acc = 0.f;
#pragma unroll 7
    for (int p = 0; p < 49; ++p) acc += sa[pg * 49 + p] * bf2f(e[(size_t)p * 2048]);
    sred[pg][q][l] = acc;
    __syncthreads();
    if (tid < 256) {
        int q2 = tid >> 6, l2 = tid & 63;
        int gc2 = q2 * 512 + u * 64 + l2;
        float s = (sred[0][q2][l2] + sred[1][q2][l2] + sred[2][q2][l2]
                   + sred[3][q2][l2]) * inv
                + b_ih[gc2] + b_hh[gc2]
                + gpre[((size_t)b * 20 + t) * 2048 + gc2]
                + ghh[(size_t)b * 2048 + gc2];
        sg[q2][l2] = s;
    }
    __syncthreads();
    if (tid < 64) {
        int j = u * 64 + tid;
        float gi = sg[0][tid], gf = sg[1][tid], gg = sg[2][tid], go = sg[3][tid];
        float si = 1.f / (1.f + expf(-gi));
        float sf = 1.f / (1.f + expf(-gf));
        float so = 1.f / (1.f + expf(-go));
        float c2 = sf * cbuf[b * 512 + j] + si * tanhf(gg);
        cbuf[b * 512 + j] = c2;
        u16 hb = f2bf(so * tanhf(c2));
        hbf[b * 512 + j] = hb;
        hallbf[(b * 20 + t) * 512 + j] = hb;
    }
}

// ---------------------------------------------------------------------------
// logits (batched over all t): hall(640x512) @ fc_W^T(512x10000) + fc_b
// r20: static LDS buffers (r12 mechanism, proven on k_encxw: -18%).
// ---------------------------------------------------------------------------
__global__ __launch_bounds__(256) void k_logits(const u16* __restrict__ hallbf,
                                                const u16* __restrict__ fcWbf,
                                                const float* __restrict__ fc_b,
                                                float* __restrict__ out) {
    __shared__ u16 As0[128 * 32], As1[128 * 32];
    __shared__ u16 Bs0[128 * 32], Bs1[128 * 32];
    int tid = threadIdx.x, lane = tid & 63, w = tid >> 6;
    int wr = w >> 1, wc = w & 1;
    int i0 = blockIdx.x * 128, j0 = blockIdx.y * 128;
    int ar = lane & 15, kg = lane >> 4;

    int srow = tid >> 2;                 // 0..63
    int sc = (tid & 3) * 8;              // u16 col within 32
    int brow0 = min(j0 + srow, NV - 1);        // clamp: keep reads in-bounds
    int brow1 = min(j0 + 64 + srow, NV - 1);
    const u16* gA0 = hallbf + (size_t)(i0 + srow) * HH + sc;
    const u16* gA1 = hallbf + (size_t)(i0 + 64 + srow) * HH + sc;
    const u16* gB0 = fcWbf + (size_t)brow0 * HH + sc;
    const u16* gB1 = fcWbf + (size_t)brow1 * HH + sc;

    f32x4 acc[4][4] = {};

#define STAGE_LG(A_, B_, k0)                                \
    do {                                                    \
        gld16(gA0 + (k0), &A_[tid * 8]);                    \
        gld16(gA1 + (k0), &A_[2048 + tid * 8]);             \
        gld16(gB0 + (k0), &B_[tid * 8]);                    \
        gld16(gB1 + (k0), &B_[2048 + tid * 8]);             \
    } while (0)

#define COMPUTE_LG(A_, B_)                                                     \
    do {                                                                       \
        bf8 a[4], b[4];                                                        \
        _Pragma("unroll") for (int m = 0; m < 4; ++m)                          \
            a[m] = *(const bf8*)(&A_[(wr * 64 + m * 16 + ar) * 32 + kg * 8]);  \
        _Pragma("unroll") for (int n = 0; n < 4; ++n)                          \
            b[n] = *(const bf8*)(&B_[(wc * 64 + n * 16 + ar) * 32 + kg * 8]);  \
        _Pragma("unroll") for (int m = 0; m < 4; ++m)                          \
            _Pragma("unroll") for (int n = 0; n < 4; ++n)                      \
                acc[m][n] = __builtin_amdgcn_mfma_f32_16x16x32_bf16(           \
                    a[m], b[n], acc[m][n], 0, 0, 0);                           \
    } while (0)

    STAGE_LG(As0, Bs0, 0);
    __syncthreads();
    for (int ks = 0; ks < 16; ks += 2) {
        STAGE_LG(As1, Bs1, (ks + 1) * 32);
        COMPUTE_LG(As0, Bs0);
        __syncthreads();
        if (ks < 14) STAGE_LG(As0, Bs0, (ks + 2) * 32);
        COMPUTE_LG(As1, Bs1);
        if (ks < 14) __syncthreads();
    }
#undef STAGE_LG
#undef COMPUTE_LG

    int rbase = kg * 4;
#pragma unroll
    for (int m = 0; m < 4; ++m) {
        int row = i0 + wr * 64 + m * 16 + rbase;
#pragma unroll
        for (int n = 0; n < 4; ++n) {
            int col = j0 + wc * 64 + n * 16 + ar;
            if (col < NV) {
                float bias = fc_b[col];
#pragma unroll
                for (int r = 0; r < 4; ++r)
                    out[(size_t)(row + r) * NV + col] = acc[m][n][r] + bias;
            }
        }
    }
}

// ---------------------------------------------------------------------------
extern "C" void kernel_launch(void* const* d_in, const int* in_sizes, int n_in,
                              void* d_out, int out_size, void* d_ws, size_t ws_size,
                              hipStream_t stream) {
    (void)in_sizes; (void)n_in; (void)out_size; (void)ws_size;
    const float* enc   = (const float*)d_in[0];
    const int*   caps  = (const int*)d_in[1];
    const float* emb   = (const float*)d_in[2];
    const float* enc_W = (const float*)d_in[3];
    const float* enc_b = (const float*)d_in[4];
    const float* dec_W = (const float*)d_in[5];
    const float* dec_b = (const float*)d_in[6];
    const float* att_W = (const float*)d_in[7];
    const float* att_b = (const float*)d_in[8];
    const float* W_ih  = (const float*)d_in[9];
    const float* W_hh  = (const float*)d_in[10];
    const float* b_ih  = (const float*)d_in[11];
    const float* b_hh  = (const float*)d_in[12];
    const float* fc_W  = (const float*)d_in[13];
    const float* fc_b  = (const float*)d_in[14];
    float* out = (float*)d_out;

    char* base = (char*)d_ws;
    float* dpartf  = (float*)base;                 base += (size_t)32 * 512 * 4;
    float* attb    = (float*)base;                 base += (size_t)6272 * 4;
    float* cbuf    = (float*)base;                 base += (size_t)32 * 512 * 4;
    float* ghh     = (float*)base;                 base += (size_t)32 * 2048 * 4;
    float* gpre    = (float*)base;                 base += (size_t)640 * 2048 * 4;
    u16* encprojbf = (u16*)base;                   base += (size_t)6272 * 512 * 2;
    u16* Xbf    = (u16*)base;                      base += (size_t)32 * 196 * 2048 * 2;
    u16* Wencbf = (u16*)base;                      base += (size_t)512 * 2048 * 2;
    u16* decWbf = (u16*)base;                      base += (size_t)512 * 512 * 2;
    u16* Wihbf  = (u16*)base;                      base += (size_t)2048 * 2560 * 2;
    u16* Whhbf  = (u16*)base;                      base += (size_t)2048 * 512 * 2;
    u16* fcWbf  = (u16*)base;                      base += (size_t)10000 * 512 * 2;
    u16* embg   = (u16*)base;                      base += (size_t)32 * 20 * 512 * 2;
    u16* XWbf   = (u16*)base;                      base += (size_t)6272 * 2048 * 2;
    u16* hbf    = (u16*)base;                      base += (size_t)32 * 512 * 2;
    u16* hallbf = (u16*)base;                      base += (size_t)32 * 20 * 512 * 2;

    k_convert<<<12660, 256, 0, stream>>>(enc, enc_W, dec_W, W_ih, W_hh, fc_W, emb, caps,
                                         Xbf, Wencbf, decWbf, Wihbf, Whhbf, fcWbf,
                                         embg, cbuf, hbf);
    k_encxw<<<dim3(49, 20), 256, 0, stream>>>(Xbf, Wencbf, Wihbf, enc_b,
                                              encprojbf, XWbf);
    k_gpre<<<dim3(10, 16), 256, 0, stream>>>(embg, Wihbf, gpre);
    for (int t = 0; t < NT; ++t) {
        k_hproj<<<80, 256, 0, stream>>>(hbf, decWbf, Whhbf, dec_b, dpartf, ghh);
        k_attexp<<<1568, 256, 0, stream>>>(encprojbf, dpartf, att_W, att_b, attb);
        k_ctxgcell<<<256, 1024, 0, stream>>>(attb, XWbf, gpre, ghh, b_ih, b_hh,
                                             cbuf, hbf, hallbf, t);
    }
    k_logits<<<dim3(5, 79), 256, 0, stream>>>(hallbf, fcWbf, fc_b, out);
}